// Round 2
// baseline (246.816 us; speedup 1.0000x reference)
//
#include <hip/hip_runtime.h>
#include <math.h>

#define IMG_H 512
#define IMG_W 512
#define NPLANES 48
#define TX 64
#define TY 32
#define RX (TX + 10)      // 74 input cols needed
#define RY (TY + 10)      // 42 input rows needed
#define SSTRIDE 76        // padded LDS row stride (16B-aligned rows)
#define BLOCK 256

// main kernel: one block = one 32x64 output tile of one (n,c) plane.
__global__ __launch_bounds__(BLOCK, 2)
void ssim_main(const float* __restrict__ img1, const float* __restrict__ img2,
               float* __restrict__ blocksums) {
    __shared__ float s1[RY * SSTRIDE];
    __shared__ float s2[RY * SSTRIDE];
    __shared__ float hs[5 * RY * TX];   // horizontal-pass results, 5 fields
    __shared__ float sg[11];
    __shared__ float red[4];

    const int tid = threadIdx.x;
    const int x0 = blockIdx.x * TX;
    const int y0 = blockIdx.y * TY;
    const float* i1 = img1 + (size_t)blockIdx.z * (IMG_H * IMG_W);
    const float* i2 = img2 + (size_t)blockIdx.z * (IMG_H * IMG_W);

    // Gaussian window (normalized), computed once per block. expf accuracy
    // ~1ulp; threshold is 2.6e-4 so this is far below noise.
    if (tid == 0) {
        float t[11], s = 0.f;
        #pragma unroll
        for (int i = 0; i < 11; ++i) {
            float d = (float)(i - 5);
            t[i] = expf(-d * d / 4.5f);
            s += t[i];
        }
        #pragma unroll
        for (int i = 0; i < 11; ++i) sg[i] = t[i] / s;
    }

    // ---- Stage A: global -> LDS (zero-padded halo) ----
    for (int idx = tid; idx < RY * RX; idx += BLOCK) {
        int r = idx / RX;
        int c = idx - r * RX;
        int gy = y0 - 5 + r;
        int gx = x0 - 5 + c;
        float v1 = 0.f, v2 = 0.f;
        if ((unsigned)gy < IMG_H && (unsigned)gx < IMG_W) {
            int g = gy * IMG_W + gx;
            v1 = i1[g];
            v2 = i2[g];
        }
        s1[r * SSTRIDE + c] = v1;
        s2[r * SSTRIDE + c] = v2;
    }
    __syncthreads();

    float w[11];
    #pragma unroll
    for (int i = 0; i < 11; ++i) w[i] = sg[i];

    // ---- Stage B: horizontal pass, 4 output columns per task ----
    // task = (row r in [0,42), col-quad c0/4 in [0,16))
    for (int t = tid; t < RY * 16; t += BLOCK) {
        int r = t >> 4;
        int c0 = (t & 15) << 2;
        float a[16], b[16];
        {
            const float4* p1 = reinterpret_cast<const float4*>(&s1[r * SSTRIDE + c0]);
            const float4* p2 = reinterpret_cast<const float4*>(&s2[r * SSTRIDE + c0]);
            #pragma unroll
            for (int q = 0; q < 4; ++q) {
                float4 v = p1[q];
                a[4*q+0] = v.x; a[4*q+1] = v.y; a[4*q+2] = v.z; a[4*q+3] = v.w;
                float4 u = p2[q];
                b[4*q+0] = u.x; b[4*q+1] = u.y; b[4*q+2] = u.z; b[4*q+3] = u.w;
            }
        }
        // products for the 14 needed positions (j in 0..3, k in 0..10 -> i<=13)
        float xx[14], yy[14], xy[14];
        #pragma unroll
        for (int i = 0; i < 14; ++i) {
            xx[i] = a[i] * a[i];
            yy[i] = b[i] * b[i];
            xy[i] = a[i] * b[i];
        }
        float ac0[4] = {0,0,0,0}, ac1[4] = {0,0,0,0}, ac2[4] = {0,0,0,0};
        float ac3[4] = {0,0,0,0}, ac4[4] = {0,0,0,0};
        #pragma unroll
        for (int k = 0; k < 11; ++k) {
            #pragma unroll
            for (int j = 0; j < 4; ++j) {
                int i = k + j;
                ac0[j] += w[k] * a[i];
                ac1[j] += w[k] * b[i];
                ac2[j] += w[k] * xx[i];
                ac3[j] += w[k] * yy[i];
                ac4[j] += w[k] * xy[i];
            }
        }
        int ho = r * TX + c0;
        *reinterpret_cast<float4*>(&hs[0 * RY * TX + ho]) = make_float4(ac0[0], ac0[1], ac0[2], ac0[3]);
        *reinterpret_cast<float4*>(&hs[1 * RY * TX + ho]) = make_float4(ac1[0], ac1[1], ac1[2], ac1[3]);
        *reinterpret_cast<float4*>(&hs[2 * RY * TX + ho]) = make_float4(ac2[0], ac2[1], ac2[2], ac2[3]);
        *reinterpret_cast<float4*>(&hs[3 * RY * TX + ho]) = make_float4(ac3[0], ac3[1], ac3[2], ac3[3]);
        *reinterpret_cast<float4*>(&hs[4 * RY * TX + ho]) = make_float4(ac4[0], ac4[1], ac4[2], ac4[3]);
    }
    __syncthreads();

    // ---- Stage C: vertical pass (4 output rows per task) + SSIM ----
    float lsum = 0.f;
    for (int t = tid; t < 8 * 64; t += BLOCK) {
        int c = t & 63;
        int r0 = (t >> 6) << 2;
        float acc[5][4];
        #pragma unroll
        for (int f = 0; f < 5; ++f) {
            float hv[14];
            #pragma unroll
            for (int i = 0; i < 14; ++i)
                hv[i] = hs[f * RY * TX + (r0 + i) * TX + c];
            #pragma unroll
            for (int j = 0; j < 4; ++j) {
                float s = 0.f;
                #pragma unroll
                for (int k = 0; k < 11; ++k) s += w[k] * hv[k + j];
                acc[f][j] = s;
            }
        }
        #pragma unroll
        for (int j = 0; j < 4; ++j) {
            float mu1 = acc[0][j], mu2 = acc[1][j];
            float ex2 = acc[2][j], ey2 = acc[3][j], exy = acc[4][j];
            float mu1s = mu1 * mu1;
            float mu2s = mu2 * mu2;
            float mu12 = mu1 * mu2;
            float s1q = ex2 - mu1s;
            float s2q = ey2 - mu2s;
            float s12 = exy - mu12;
            float v1 = 2.f * s12 + 9e-4f;
            float v2 = s1q + s2q + 9.01e-4f;          // C2 + 1e-6
            float num = (2.f * mu12 + 1e-4f) * v1;    // C1 = 1e-4
            float den = (mu1s + mu2s + 1e-4f) * v2;
            lsum += num / den;
        }
    }

    // ---- block reduction -> one float per block (poison-safe: every slot written) ----
    #pragma unroll
    for (int off = 32; off; off >>= 1) lsum += __shfl_down(lsum, off, 64);
    int wave = tid >> 6;
    if ((tid & 63) == 0) red[wave] = lsum;
    __syncthreads();
    if (tid == 0) {
        float bs = red[0] + red[1] + red[2] + red[3];
        int bid = (blockIdx.z * gridDim.y + blockIdx.y) * gridDim.x + blockIdx.x;
        blocksums[bid] = bs;
    }
}

__global__ void ssim_finalize(const float* __restrict__ bs, float* __restrict__ out, int n) {
    __shared__ double red[4];
    double s = 0.0;
    for (int i = threadIdx.x; i < n; i += BLOCK) s += (double)bs[i];
    #pragma unroll
    for (int off = 32; off; off >>= 1) s += __shfl_down(s, off, 64);
    if ((threadIdx.x & 63) == 0) red[threadIdx.x >> 6] = s;
    __syncthreads();
    if (threadIdx.x == 0)
        out[0] = (float)((red[0] + red[1] + red[2] + red[3]) / 12582912.0);
}

extern "C" void kernel_launch(void* const* d_in, const int* in_sizes, int n_in,
                              void* d_out, int out_size, void* d_ws, size_t ws_size,
                              hipStream_t stream) {
    const float* img1 = (const float*)d_in[0];
    const float* img2 = (const float*)d_in[1];
    float* out = (float*)d_out;
    float* bsums = (float*)d_ws;   // 6144 floats, all written every launch

    dim3 grid(IMG_W / TX, IMG_H / TY, NPLANES);   // 8 x 16 x 48 = 6144 blocks
    ssim_main<<<grid, BLOCK, 0, stream>>>(img1, img2, bsums);
    ssim_finalize<<<1, BLOCK, 0, stream>>>(bsums, out, 6144);
}

// Round 3
// 179.684 us; speedup vs baseline: 1.3736x; 1.3736x over previous
//
#include <hip/hip_runtime.h>
#include <math.h>

#define IMG_H 512
#define IMG_W 512
#define NPLANES 48
#define TX 64          // output tile width
#define TY 32          // output tile height
#define VW 74          // staged cols = TX + 10 (input col halo)
#define VSTRIDE 75     // odd stride: H-pass 4row x 16quad pattern -> 2-way (free)
#define NF 5
#define BLOCK 256

// Vertical pass for one (column c, 4-row group r0), fields accumulated in regs.
// BORDER=true adds zero-pad guards; interior blocks skip them.
template <bool BORDER>
__device__ __forceinline__ void vpass(const float* __restrict__ i1,
                                      const float* __restrict__ i2,
                                      float* __restrict__ vs,
                                      const float* w,
                                      int x0, int y0, int tid) {
    // tasks: 74 cols x 8 row-quads = 592
    for (int t = tid; t < VW * (TY / 4); t += BLOCK) {
        int r0 = (t / VW) * 4;
        int c  = t - (t / VW) * VW;
        int gx = x0 - 5 + c;
        float acc[NF][4];
        #pragma unroll
        for (int f = 0; f < NF; ++f)
            #pragma unroll
            for (int j = 0; j < 4; ++j) acc[f][j] = 0.f;

        #pragma unroll
        for (int i = 0; i < 14; ++i) {
            int gy = y0 + r0 - 5 + i;
            float a, b;
            if (BORDER) {
                bool ok = ((unsigned)gy < IMG_H) & ((unsigned)gx < IMG_W);
                int g = ok ? gy * IMG_W + gx : 0;
                a = i1[g]; b = i2[g];
                a = ok ? a : 0.f;
                b = ok ? b : 0.f;
            } else {
                int g = gy * IMG_W + gx;
                a = i1[g]; b = i2[g];
            }
            float aa = a * a, bb = b * b, ab = a * b;
            #pragma unroll
            for (int j = 0; j < 4; ++j) {
                int k = i - j;                 // compile-time per (i,j)
                if (k >= 0 && k < 11) {
                    float wk = w[k];
                    acc[0][j] += wk * a;
                    acc[1][j] += wk * b;
                    acc[2][j] += wk * aa;
                    acc[3][j] += wk * bb;
                    acc[4][j] += wk * ab;
                }
            }
        }
        #pragma unroll
        for (int f = 0; f < NF; ++f)
            #pragma unroll
            for (int j = 0; j < 4; ++j)
                vs[f * TY * VSTRIDE + (r0 + j) * VSTRIDE + c] = acc[f][j];
    }
}

__global__ __launch_bounds__(BLOCK, 3)
void ssim_main(const float* __restrict__ img1, const float* __restrict__ img2,
               float* __restrict__ blocksums) {
    __shared__ float vs[NF * TY * VSTRIDE];   // 5*32*75*4 = 48000 B -> 3 blocks/CU
    __shared__ float red[4];

    const int tid = threadIdx.x;
    const int x0 = blockIdx.x * TX;
    const int y0 = blockIdx.y * TY;
    const float* i1 = img1 + (size_t)blockIdx.z * (IMG_H * IMG_W);
    const float* i2 = img2 + (size_t)blockIdx.z * (IMG_H * IMG_W);

    // Gaussian window, computed redundantly per thread (uniform, deterministic).
    // ~60 VALU ops once per thread; avoids an LDS broadcast + extra barrier.
    float w[11];
    {
        float t[11], s = 0.f;
        #pragma unroll
        for (int i = 0; i < 11; ++i) {
            float d = (float)(i - 5);
            t[i] = expf(-d * d / 4.5f);
            s += t[i];
        }
        #pragma unroll
        for (int i = 0; i < 11; ++i) w[i] = t[i] / s;
    }

    // ---- Phase V: global (L1/L2-cached re-reads) -> vertical conv -> LDS ----
    bool border = (blockIdx.x == 0) | (blockIdx.x == gridDim.x - 1) |
                  (blockIdx.y == 0) | (blockIdx.y == gridDim.y - 1);
    if (border) vpass<true >(i1, i2, vs, w, x0, y0, tid);
    else        vpass<false>(i1, i2, vs, w, x0, y0, tid);
    __syncthreads();

    // ---- Phase H: horizontal conv from LDS + SSIM + thread-local sum ----
    float lsum = 0.f;
    for (int t = tid; t < TY * 16; t += BLOCK) {       // 512 tasks, exactly 2/thread
        int r  = t >> 4;
        int c0 = (t & 15) << 2;
        float acc[NF][4];
        #pragma unroll
        for (int f = 0; f < NF; ++f) {
            const float* vp = &vs[f * TY * VSTRIDE + r * VSTRIDE + c0];
            float hv[14];
            #pragma unroll
            for (int i = 0; i < 14; ++i) hv[i] = vp[i];
            #pragma unroll
            for (int j = 0; j < 4; ++j) {
                float s = 0.f;
                #pragma unroll
                for (int k = 0; k < 11; ++k) s += w[k] * hv[k + j];
                acc[f][j] = s;
            }
        }
        #pragma unroll
        for (int j = 0; j < 4; ++j) {
            float mu1 = acc[0][j], mu2 = acc[1][j];
            float ex2 = acc[2][j], ey2 = acc[3][j], exy = acc[4][j];
            float mu1s = mu1 * mu1;
            float mu2s = mu2 * mu2;
            float mu12 = mu1 * mu2;
            float s1q = ex2 - mu1s;
            float s2q = ey2 - mu2s;
            float s12 = exy - mu12;
            float v1 = 2.f * s12 + 9e-4f;
            float v2 = s1q + s2q + 9.01e-4f;          // C2 + 1e-6
            float num = (2.f * mu12 + 1e-4f) * v1;    // C1 = 1e-4
            float den = (mu1s + mu2s + 1e-4f) * v2;
            lsum += num / den;
        }
    }

    // ---- block reduction -> one float per block ----
    #pragma unroll
    for (int off = 32; off; off >>= 1) lsum += __shfl_down(lsum, off, 64);
    if ((tid & 63) == 0) red[tid >> 6] = lsum;
    __syncthreads();
    if (tid == 0) {
        float bs = red[0] + red[1] + red[2] + red[3];
        int bid = (blockIdx.z * gridDim.y + blockIdx.y) * gridDim.x + blockIdx.x;
        blocksums[bid] = bs;
    }
}

__global__ void ssim_finalize(const float* __restrict__ bs, float* __restrict__ out, int n) {
    __shared__ double red[4];
    double s = 0.0;
    for (int i = threadIdx.x; i < n; i += BLOCK) s += (double)bs[i];
    #pragma unroll
    for (int off = 32; off; off >>= 1) s += __shfl_down(s, off, 64);
    if ((threadIdx.x & 63) == 0) red[threadIdx.x >> 6] = s;
    __syncthreads();
    if (threadIdx.x == 0)
        out[0] = (float)((red[0] + red[1] + red[2] + red[3]) / 12582912.0);
}

extern "C" void kernel_launch(void* const* d_in, const int* in_sizes, int n_in,
                              void* d_out, int out_size, void* d_ws, size_t ws_size,
                              hipStream_t stream) {
    const float* img1 = (const float*)d_in[0];
    const float* img2 = (const float*)d_in[1];
    float* out = (float*)d_out;
    float* bsums = (float*)d_ws;   // 6144 floats, all written every launch

    dim3 grid(IMG_W / TX, IMG_H / TY, NPLANES);   // 8 x 16 x 48 = 6144 blocks
    ssim_main<<<grid, BLOCK, 0, stream>>>(img1, img2, bsums);
    ssim_finalize<<<1, BLOCK, 0, stream>>>(bsums, out, 6144);
}